// Round 10
// baseline (340.512 us; speedup 1.0000x reference)
//
#include <hip/hip_runtime.h>

#define N_NODES 40000
#define E_EDGES 640000
#define DIM 128
#define NBKT 157            // buckets of 256 rows
#define BKT_CAP 6144

typedef __attribute__((ext_vector_type(8))) short short8;
typedef __attribute__((ext_vector_type(4))) float f32x4;

__device__ __forceinline__ unsigned short f2bf(float f) {
    unsigned int u = __float_as_uint(f);
    u = u + 0x7FFFu + ((u >> 16) & 1u);
    return (unsigned short)(u >> 16);
}
__device__ __forceinline__ unsigned int pack2bf(float lo, float hi) {
    return (unsigned int)f2bf(lo) | ((unsigned int)f2bf(hi) << 16);
}
__device__ __forceinline__ float2 unpack2bf(unsigned int u) {
    return make_float2(__uint_as_float(u << 16), __uint_as_float(u & 0xFFFF0000u));
}
__device__ __forceinline__ short8 pack_bf8(float4 a, float4 b) {
    short8 r;
    r[0] = (short)f2bf(a.x); r[1] = (short)f2bf(a.y);
    r[2] = (short)f2bf(a.z); r[3] = (short)f2bf(a.w);
    r[4] = (short)f2bf(b.x); r[5] = (short)f2bf(b.y);
    r[6] = (short)f2bf(b.z); r[7] = (short)f2bf(b.w);
    return r;
}

// ===========================================================================
// Fused prep: blocks [0, nP1) do CSR bucket partition (build_p1);
// blocks [nP1, nP1+nCv) do fp32->bf16 feature conversion.
// ===========================================================================
__global__ __launch_bounds__(256) void prep_kernel(
    const int* __restrict__ rows, const int* __restrict__ cols,
    const float* __restrict__ vals,
    int* __restrict__ bktCnt,
    uint2* __restrict__ stagedA, uint2* __restrict__ stagedT,
    const float4* __restrict__ lf, const float4* __restrict__ rf,
    uint2* __restrict__ l16, uint2* __restrict__ r16,
    int nP1, int n4)
{
    const int tid = threadIdx.x;
    if ((int)blockIdx.x >= nP1) {
        // ---------------- convert part ----------------
        int i = (blockIdx.x - nP1) * 256 + tid;
        if (i < n4) {
            float4 a = lf[i];
            float4 b = rf[i];
            l16[i] = make_uint2(pack2bf(a.x, a.y), pack2bf(a.z, a.w));
            r16[i] = make_uint2(pack2bf(b.x, b.y), pack2bf(b.z, b.w));
        }
        return;
    }
    // ---------------- build_p1 part ----------------
    __shared__ int cA[NBKT], cT[NBKT], bA[NBKT], bT[NBKT];
    for (int i = tid; i < NBKT; i += 256) { cA[i] = 0; cT[i] = 0; }
    __syncthreads();

    int r[8], c[8];
    unsigned int v[8];
    const int base = blockIdx.x * 2048 + tid;
    #pragma unroll
    for (int k = 0; k < 8; ++k) {
        int e = base + k * 256;
        bool ok = e < E_EDGES;
        r[k] = ok ? __builtin_nontemporal_load(rows + e) : -1;
        c[k] = ok ? __builtin_nontemporal_load(cols + e) : 0;
        v[k] = ok ? __float_as_uint(__builtin_nontemporal_load(vals + e)) : 0u;
        if (ok) {
            atomicAdd(&cA[r[k] >> 8], 1);
            atomicAdd(&cT[c[k] >> 8], 1);
        }
    }
    __syncthreads();
    for (int i = tid; i < NBKT; i += 256) {
        bA[i] = atomicAdd(&bktCnt[i], cA[i]);
        bT[i] = atomicAdd(&bktCnt[NBKT + i], cT[i]);
        cA[i] = 0; cT[i] = 0;
    }
    __syncthreads();
    #pragma unroll
    for (int k = 0; k < 8; ++k) {
        if (r[k] < 0) continue;
        int ba = r[k] >> 8;
        int pa = bA[ba] + atomicAdd(&cA[ba], 1);
        if (pa < BKT_CAP) {
            unsigned long long rec =
                ((unsigned long long)v[k] << 32) |
                (((unsigned)r[k] << 16) | (unsigned)c[k]);
            __builtin_nontemporal_store(rec,
                (unsigned long long*)(stagedA + (size_t)ba * BKT_CAP + pa));
        }
        int bt = c[k] >> 8;
        int pt = bT[bt] + atomicAdd(&cT[bt], 1);
        if (pt < BKT_CAP) {
            unsigned long long rec =
                ((unsigned long long)v[k] << 32) |
                (((unsigned)c[k] << 16) | (unsigned)r[k]);
            __builtin_nontemporal_store(rec,
                (unsigned long long*)(stagedT + (size_t)bt * BKT_CAP + pt));
        }
    }
}

__global__ __launch_bounds__(256) void bkt_scan(
    const int* __restrict__ bktCnt, int* __restrict__ bktBase,
    int* __restrict__ rpA, int* __restrict__ rpT)
{
    __shared__ int s[2][256];
    const int tid = threadIdx.x;
    for (int d = 0; d < 2; ++d) {
        int v = (tid < NBKT) ? min(bktCnt[d * NBKT + tid], BKT_CAP) : 0;
        s[0][tid] = v;
        __syncthreads();
        int sel = 0;
        for (int off = 1; off < 256; off <<= 1) {
            int t = s[sel][tid] + ((tid >= off) ? s[sel][tid - off] : 0);
            s[sel ^ 1][tid] = t;
            sel ^= 1;
            __syncthreads();
        }
        int incl = s[sel][tid];
        if (tid < NBKT) bktBase[d * NBKT + tid] = incl - v;
        if (tid == NBKT - 1) (d ? rpT : rpA)[N_NODES] = incl;
        __syncthreads();
    }
}

__global__ __launch_bounds__(256) void build_p2(
    const int* __restrict__ bktCnt, const int* __restrict__ bktBase,
    const uint2* __restrict__ stagedA, const uint2* __restrict__ stagedT,
    int* __restrict__ rpA, int* __restrict__ rpT,
    int2* __restrict__ cvA, int2* __restrict__ cvT)
{
    const int tid = threadIdx.x;
    int dir = (int)blockIdx.x >= NBKT;
    int b = blockIdx.x - dir * NBKT;
    int cnt = min(bktCnt[dir * NBKT + b], BKT_CAP);
    int cbase = bktBase[dir * NBKT + b];
    const uint2* staged = (dir ? stagedT : stagedA) + (size_t)b * BKT_CAP;
    int* rp = dir ? rpT : rpA;
    int2* cv = dir ? cvT : cvA;

    __shared__ int rc[256];
    __shared__ int s[2][256];
    rc[tid] = 0;
    __syncthreads();
    for (int i = tid; i < cnt; i += 256) {
        unsigned long long rec = __builtin_nontemporal_load(
            (const unsigned long long*)(staged + i));
        atomicAdd(&rc[((unsigned)(rec & 0xFFFFFFFFull) >> 16) & 255], 1);
    }
    __syncthreads();
    int own = rc[tid];
    s[0][tid] = own;
    __syncthreads();
    int sel = 0;
    for (int off = 1; off < 256; off <<= 1) {
        int t = s[sel][tid] + ((tid >= off) ? s[sel][tid - off] : 0);
        s[sel ^ 1][tid] = t;
        sel ^= 1;
        __syncthreads();
    }
    int ex = s[sel][tid] - own;
    int row = b * 256 + tid;
    if (row < N_NODES) rp[row] = cbase + ex;
    rc[tid] = ex;
    __syncthreads();
    for (int i = tid; i < cnt; i += 256) {
        unsigned long long rec = __builtin_nontemporal_load(
            (const unsigned long long*)(staged + i));
        unsigned lo = (unsigned)(rec & 0xFFFFFFFFull);
        int local = (lo >> 16) & 255;
        int pos = cbase + atomicAdd(&rc[local], 1);
        // store col as BYTE offset (col * 256) for cheap gather addressing
        cv[pos] = make_int2((int)((lo & 0xFFFFu) << 8), (int)(rec >> 32));
    }
}

// ===========================================================================
// Generic SpMM: 16 lanes/edge, 16B/lane, 4 edge sub-streams.
//   t = M @ g16
// Row-local inputs (all bf16 rows): s16 (multiplier for t), pa16 (prior a),
// ps16 (prior a's multiplier). Stores (nullable):
//   a16 = bf( t + pa )                 [sub0]
//   m16 = bf( t*s + pa*ps )           [sub1]
//   k16 = bf( t + t*s )               [sub2]
// cv.x holds col*256 (byte offset); cv loads are nontemporal (zero reuse).
// Two sets per dispatch (blocks >= nA -> set B).
// ===========================================================================
struct SpSet {
    const int* rp;
    const int2* cv;
    const unsigned int* g16;
    const unsigned int* s16;
    const unsigned int* pa16;
    const unsigned int* ps16;
    unsigned int* a16;
    unsigned int* m16;
    unsigned int* k16;
};

__device__ __forceinline__ void sp_accum(float* acc, uint4 w, float v) {
    float2 f;
    f = unpack2bf(w.x); acc[0] = fmaf(v, f.x, acc[0]); acc[1] = fmaf(v, f.y, acc[1]);
    f = unpack2bf(w.y); acc[2] = fmaf(v, f.x, acc[2]); acc[3] = fmaf(v, f.y, acc[3]);
    f = unpack2bf(w.z); acc[4] = fmaf(v, f.x, acc[4]); acc[5] = fmaf(v, f.y, acc[5]);
    f = unpack2bf(w.w); acc[6] = fmaf(v, f.x, acc[6]); acc[7] = fmaf(v, f.y, acc[7]);
}
__device__ __forceinline__ int2 ld_cv_nt(const int2* p) {
    unsigned long long u = __builtin_nontemporal_load((const unsigned long long*)p);
    return make_int2((int)(u & 0xFFFFFFFFull), (int)(u >> 32));
}
__device__ __forceinline__ void unp8(uint4 v, float* f) {
    float2 t;
    t = unpack2bf(v.x); f[0] = t.x; f[1] = t.y;
    t = unpack2bf(v.y); f[2] = t.x; f[3] = t.y;
    t = unpack2bf(v.z); f[4] = t.x; f[5] = t.y;
    t = unpack2bf(v.w); f[6] = t.x; f[7] = t.y;
}

__global__ __launch_bounds__(256) void sp_multi(SpSet sA, SpSet sB, int nA)
{
    bool second = (int)blockIdx.x >= nA;
    SpSet st = second ? sB : sA;
    int blk = second ? (blockIdx.x - nA) : blockIdx.x;
    int row = blk * 4 + (threadIdx.x >> 6);
    if (row >= N_NODES) return;
    int lane = threadIdx.x & 63;
    int li = lane & 15;
    int sub = lane >> 4;

    int b = st.rp[row], e = st.rp[row + 1];
    int o = row * 16 + li;       // uint4 index into row-local streams

    // row-local companion reads issued early; overlap the gather loop
    uint4 sv4 = ((const uint4*)st.s16)[o];
    uint4 pav4 = st.pa16 ? ((const uint4*)st.pa16)[o] : make_uint4(0,0,0,0);
    uint4 psv4 = st.ps16 ? ((const uint4*)st.ps16)[o] : make_uint4(0,0,0,0);

    float acc[8] = {0.f, 0.f, 0.f, 0.f, 0.f, 0.f, 0.f, 0.f};
    const char* gbase = (const char*)st.g16 + li * 16;

    int i = b + sub;
    for (; i + 12 < e; i += 16) {
        int2 c0 = ld_cv_nt(st.cv + i);
        int2 c1 = ld_cv_nt(st.cv + i + 4);
        int2 c2 = ld_cv_nt(st.cv + i + 8);
        int2 c3 = ld_cv_nt(st.cv + i + 12);
        uint4 w0 = *(const uint4*)(gbase + (unsigned)c0.x);
        uint4 w1 = *(const uint4*)(gbase + (unsigned)c1.x);
        uint4 w2 = *(const uint4*)(gbase + (unsigned)c2.x);
        uint4 w3 = *(const uint4*)(gbase + (unsigned)c3.x);
        sp_accum(acc, w0, __int_as_float(c0.y));
        sp_accum(acc, w1, __int_as_float(c1.y));
        sp_accum(acc, w2, __int_as_float(c2.y));
        sp_accum(acc, w3, __int_as_float(c3.y));
    }
    for (; i + 4 < e; i += 8) {
        int2 c0 = ld_cv_nt(st.cv + i);
        int2 c1 = ld_cv_nt(st.cv + i + 4);
        uint4 w0 = *(const uint4*)(gbase + (unsigned)c0.x);
        uint4 w1 = *(const uint4*)(gbase + (unsigned)c1.x);
        sp_accum(acc, w0, __int_as_float(c0.y));
        sp_accum(acc, w1, __int_as_float(c1.y));
    }
    if (i < e) {
        int2 c = ld_cv_nt(st.cv + i);
        uint4 w = *(const uint4*)(gbase + (unsigned)c.x);
        sp_accum(acc, w, __int_as_float(c.y));
    }

    #pragma unroll
    for (int j = 0; j < 8; ++j) {
        acc[j] += __shfl_xor(acc[j], 16, 64);
        acc[j] += __shfl_xor(acc[j], 32, 64);
    }

    float s[8];
    unp8(sv4, s);

    if (sub == 0 && st.a16) {
        float a[8];
        #pragma unroll
        for (int j = 0; j < 8; ++j) a[j] = acc[j];
        if (st.pa16) {
            float pa[8]; unp8(pav4, pa);
            #pragma unroll
            for (int j = 0; j < 8; ++j) a[j] += pa[j];
        }
        ((uint4*)st.a16)[o] = make_uint4(
            pack2bf(a[0], a[1]), pack2bf(a[2], a[3]),
            pack2bf(a[4], a[5]), pack2bf(a[6], a[7]));
    } else if (sub == 1 && st.m16) {
        float q[8];
        #pragma unroll
        for (int j = 0; j < 8; ++j) q[j] = acc[j] * s[j];
        if (st.pa16) {
            float pa[8], ps[8]; unp8(pav4, pa); unp8(psv4, ps);
            #pragma unroll
            for (int j = 0; j < 8; ++j) q[j] = fmaf(pa[j], ps[j], q[j]);
        }
        ((uint4*)st.m16)[o] = make_uint4(
            pack2bf(q[0], q[1]), pack2bf(q[2], q[3]),
            pack2bf(q[4], q[5]), pack2bf(q[6], q[7]));
    } else if (sub == 2 && st.k16) {
        ((uint4*)st.k16)[o] = make_uint4(
            pack2bf(acc[0] + acc[0]*s[0], acc[1] + acc[1]*s[1]),
            pack2bf(acc[2] + acc[2]*s[2], acc[3] + acc[3]*s[3]),
            pack2bf(acc[4] + acc[4]*s[4], acc[5] + acc[5]*s[5]),
            pack2bf(acc[6] + acc[6]*s[6], acc[7] + acc[7]*s[7]));
    }
}

// ===========================================================================
// MFMA double GEMM, fragment-linear conflict-free LDS, 128-row blocks
// (two 64-row halves reuse in-register W fragments):
//   res = relu( X1@W1^T + X2@W2^T + 2*(b1+b2) )
// Two sets per dispatch (blocks >= nA -> set B). 32 KB LDS.
// ===========================================================================
struct G2 {
    const unsigned short* X1[2];
    const unsigned short* X2[2];
    float* outf[2];
    unsigned short* o16[2];
};

__global__ __launch_bounds__(256) void gemm2f(
    G2 g, const float* __restrict__ W1, const float* __restrict__ W2,
    const float* __restrict__ b1, const float* __restrict__ b2, int nA)
{
    __shared__ unsigned short xs[2][64 * DIM];   // 32 KB

    int second = (int)blockIdx.x >= nA;
    int blk = blockIdx.x - second * nA;
    const int tid = threadIdx.x;

    const unsigned short* Xs0 = g.X1[second];
    const unsigned short* Xs1 = g.X2[second];
    float* outf = g.outf[second];
    unsigned short* o16 = g.o16[second];

    const int wv = tid >> 6;
    const int lane = tid & 63;
    const int lr = lane & 15;
    const int kgrp = lane >> 4;
    const int colbase = wv * 32;

    short8 wf[2][2][4];
    #pragma unroll
    for (int mat = 0; mat < 2; ++mat) {
        const float* W = mat ? W2 : W1;
        #pragma unroll
        for (int nt = 0; nt < 2; ++nt) {
            #pragma unroll
            for (int ks = 0; ks < 4; ++ks) {
                const float* wp = W + (size_t)(colbase + nt * 16 + lr) * DIM
                                    + ks * 32 + kgrp * 8;
                wf[mat][nt][ks] = pack_bf8(*(const float4*)wp,
                                           *(const float4*)(wp + 4));
            }
        }
    }

    float cb[2];
    #pragma unroll
    for (int nt = 0; nt < 2; ++nt) {
        int col = colbase + nt * 16 + lr;
        cb[nt] = 2.0f * (b1[col] + b2[col]);
    }

    #pragma unroll
    for (int h = 0; h < 2; ++h) {
        const int row0 = blk * 128 + h * 64;
        if (h) __syncthreads();

        #pragma unroll
        for (int t = 0; t < 2; ++t) {
            const unsigned short* X = t ? Xs1 : Xs0;
            #pragma unroll
            for (int it = 0; it < 4; ++it) {
                int id = tid + 256 * it;
                int r = id >> 4, c16 = id & 15;
                int ks = c16 >> 2, kg = c16 & 3;
                int mt = r >> 4, rr = r & 15;
                int addr = ((((ks * 4 + mt) * 64) + kg * 16 + rr) * 16) ^ (ks << 5);
                int grow = min(row0 + r, N_NODES - 1);
                uint4 d = *(const uint4*)(X + (size_t)grow * DIM + c16 * 8);
                *(uint4*)((char*)&xs[t][0] + addr) = d;
            }
        }
        __syncthreads();

        f32x4 acc[4][2];
        #pragma unroll
        for (int mt = 0; mt < 4; ++mt)
            #pragma unroll
            for (int nt = 0; nt < 2; ++nt)
                acc[mt][nt] = (f32x4){0.f, 0.f, 0.f, 0.f};

        #pragma unroll
        for (int ks = 0; ks < 4; ++ks) {
            short8 a1f[4], a2f[4];
            #pragma unroll
            for (int mt = 0; mt < 4; ++mt) {
                int addr = ((((ks * 4 + mt) * 64) + lane) * 16) ^ (ks << 5);
                a1f[mt] = *(const short8*)((const char*)&xs[0][0] + addr);
                a2f[mt] = *(const short8*)((const char*)&xs[1][0] + addr);
            }
            #pragma unroll
            for (int mt = 0; mt < 4; ++mt) {
                #pragma unroll
                for (int nt = 0; nt < 2; ++nt) {
                    acc[mt][nt] = __builtin_amdgcn_mfma_f32_16x16x32_bf16(
                        a1f[mt], wf[0][nt][ks], acc[mt][nt], 0, 0, 0);
                    acc[mt][nt] = __builtin_amdgcn_mfma_f32_16x16x32_bf16(
                        a2f[mt], wf[1][nt][ks], acc[mt][nt], 0, 0, 0);
                }
            }
        }

        #pragma unroll
        for (int nt = 0; nt < 2; ++nt) {
            int col = colbase + nt * 16 + lr;
            #pragma unroll
            for (int mt = 0; mt < 4; ++mt) {
                #pragma unroll
                for (int r = 0; r < 4; ++r) {
                    int row = row0 + mt * 16 + kgrp * 4 + r;
                    if (row < N_NODES) {
                        float o = fmaxf(acc[mt][nt][r] + cb[nt], 0.f);
                        if (outf) outf[(size_t)row * DIM + col] = o;
                        if (o16) o16[(size_t)row * DIM + col] = f2bf(o);
                    }
                }
            }
        }
    }
}

// ===========================================================================
extern "C" void kernel_launch(void* const* d_in, const int* in_sizes, int n_in,
                              void* d_out, int out_size, void* d_ws, size_t ws_size,
                              hipStream_t stream)
{
    const float* l_feat = (const float*)d_in[0];
    const float* r_feat = (const float*)d_in[1];
    const int*   rows   = (const int*)d_in[2];
    const int*   cols   = (const int*)d_in[3];
    const float* vals   = (const float*)d_in[4];
    const float* W1a    = (const float*)d_in[5];
    const float* b1a    = (const float*)d_in[6];
    const float* W2a    = (const float*)d_in[7];
    const float* b2a    = (const float*)d_in[8];
    const float* W1b    = (const float*)d_in[9];
    const float* b1b    = (const float*)d_in[10];
    const float* W2b    = (const float*)d_in[11];
    const float* b2b    = (const float*)d_in[12];
    float* out = (float*)d_out;

    const size_t NT = (size_t)N_NODES * DIM;
    const size_t MAT16 = NT * 2;

    char* p = (char*)d_ws;
    auto alloc = [&](size_t bytes) {
        char* q = p; p += (bytes + 255) & ~(size_t)255; return q;
    };
    unsigned int* l16 = (unsigned int*)alloc(MAT16);   // l_feat -> y1
    unsigned int* r16 = (unsigned int*)alloc(MAT16);   // r_feat -> z1
    unsigned int* Kl  = (unsigned int*)alloc(MAT16);
    unsigned int* Kr  = (unsigned int*)alloc(MAT16);
    unsigned int* aL  = (unsigned int*)alloc(MAT16);   // a-sum (L)
    unsigned int* mL  = (unsigned int*)alloc(MAT16);   // m-sum (L)
    unsigned int* aR  = (unsigned int*)alloc(MAT16);   // a-sum (R)
    unsigned int* mR  = (unsigned int*)alloc(MAT16);   // m-sum (R)
    int* rpA = (int*)alloc((size_t)(N_NODES + 1) * 4);
    int* rpT = (int*)alloc((size_t)(N_NODES + 1) * 4);
    int* bktCnt  = (int*)alloc((size_t)(2 * NBKT) * 4);
    int* bktBase = (int*)alloc((size_t)(2 * NBKT) * 4);
    int2* cvA = (int2*)alloc((size_t)E_EDGES * 8);
    int2* cvT = (int2*)alloc((size_t)E_EDGES * 8);
    uint2* stagedA = (uint2*)alloc((size_t)NBKT * BKT_CAP * 8);
    uint2* stagedT = (uint2*)alloc((size_t)NBKT * BKT_CAP * 8);

    const int n4 = (int)(NT / 4);
    dim3 blk(256);
    const int cvBlocks = (n4 + 255) / 256;         // 5000
    const int spBlocks = (N_NODES + 3) / 4;        // 10000
    const int gmBlocks = (N_NODES + 127) / 128;    // 313
    const int p1Blocks = (E_EDGES + 2047) / 2048;  // 313

    // ---- CSR build + bf16 conversion (fused) ----
    hipMemsetAsync(bktCnt, 0, (size_t)(2 * NBKT) * 4, stream);
    prep_kernel<<<dim3(p1Blocks + cvBlocks), blk, 0, stream>>>(
        rows, cols, vals, bktCnt, stagedA, stagedT,
        (const float4*)l_feat, (const float4*)r_feat,
        (uint2*)l16, (uint2*)r16, p1Blocks, n4);
    bkt_scan<<<1, blk, 0, stream>>>(bktCnt, bktBase, rpA, rpT);
    build_p2<<<dim3(2 * NBKT), blk, 0, stream>>>(
        bktCnt, bktBase, stagedA, stagedT, rpA, rpT, cvA, cvT);

    // ======================= Layer A =======================
    {   // hop0: a0=A@r -> aL, Kl ; b0=AT@l -> aR, Kr   (no m store)
        SpSet h0A = {rpA, cvA, r16, l16, nullptr, nullptr, aL, nullptr, Kl};
        SpSet h0T = {rpT, cvT, l16, r16, nullptr, nullptr, aR, nullptr, Kr};
        sp_multi<<<dim3(2 * spBlocks), blk, 0, stream>>>(h0A, h0T, spBlocks);
    }
    {   // hop1: t=A@Kr: aL=bf(a0+t), mL=bf(a0*l + t*Kl); mirror for R
        SpSet h1A = {rpA, cvA, Kr, Kl, aL, l16, aL, mL, nullptr};
        SpSet h1T = {rpT, cvT, Kl, Kr, aR, r16, aR, mR, nullptr};
        sp_multi<<<dim3(2 * spBlocks), blk, 0, stream>>>(h1A, h1T, spBlocks);
    }
    {   // y1 -> l16 (bf16), z1 -> r16 (bf16)
        G2 g;
        g.X1[0] = (const unsigned short*)aL; g.X2[0] = (const unsigned short*)mL;
        g.X1[1] = (const unsigned short*)aR; g.X2[1] = (const unsigned short*)mR;
        g.outf[0] = nullptr; g.outf[1] = nullptr;
        g.o16[0] = (unsigned short*)l16;
        g.o16[1] = (unsigned short*)r16;
        gemm2f<<<dim3(2 * gmBlocks), blk, 0, stream>>>(
            g, W1a, W2a, b1a, b2a, gmBlocks);
    }

    // ======================= Layer B (l-output only) =======================
    {   // a=A@z1 -> aL, Klb ; b=AT@y1 -> Krb only
        SpSet b0A = {rpA, cvA, r16, l16, nullptr, nullptr, aL, nullptr, Kl};
        SpSet b0T = {rpT, cvT, l16, r16, nullptr, nullptr, nullptr, nullptr, Kr};
        sp_multi<<<dim3(2 * spBlocks), blk, 0, stream>>>(b0A, b0T, spBlocks);
    }
    {   // t=A@Krb: aL=bf(a0b+t), mL=bf(a0b*y1 + t*Klb)
        SpSet b1A = {rpA, cvA, Kr, Kl, aL, l16, aL, mL, nullptr};
        sp_multi<<<dim3(spBlocks), blk, 0, stream>>>(b1A, b1A, spBlocks);
    }
    {   // out = relu(aL@W1b^T + mL@W2b^T + 2(b1b+b2b))  [fp32]
        G2 g;
        g.X1[0] = (const unsigned short*)aL; g.X2[0] = (const unsigned short*)mL;
        g.X1[1] = g.X1[0]; g.X2[1] = g.X2[0];
        g.outf[0] = out; g.outf[1] = nullptr;
        g.o16[0] = nullptr; g.o16[1] = nullptr;
        gemm2f<<<dim3(gmBlocks), blk, 0, stream>>>(
            g, W1b, W2b, b1b, b2b, gmBlocks);
    }
}

// Round 11
// 312.305 us; speedup vs baseline: 1.0903x; 1.0903x over previous
//
#include <hip/hip_runtime.h>

#define N_NODES 40000
#define E_EDGES 640000
#define DIM 128
#define NBKT 157            // buckets of 256 rows
#define BKT_CAP 6144

typedef __attribute__((ext_vector_type(8))) short short8;
typedef __attribute__((ext_vector_type(4))) float f32x4;
typedef __attribute__((ext_vector_type(4))) unsigned int u32x4;

__device__ __forceinline__ unsigned short f2bf(float f) {
    unsigned int u = __float_as_uint(f);
    u = u + 0x7FFFu + ((u >> 16) & 1u);
    return (unsigned short)(u >> 16);
}
__device__ __forceinline__ unsigned int pack2bf(float lo, float hi) {
    return (unsigned int)f2bf(lo) | ((unsigned int)f2bf(hi) << 16);
}
__device__ __forceinline__ float2 unpack2bf(unsigned int u) {
    return make_float2(__uint_as_float(u << 16), __uint_as_float(u & 0xFFFF0000u));
}
__device__ __forceinline__ short8 pack_bf8(float4 a, float4 b) {
    short8 r;
    r[0] = (short)f2bf(a.x); r[1] = (short)f2bf(a.y);
    r[2] = (short)f2bf(a.z); r[3] = (short)f2bf(a.w);
    r[4] = (short)f2bf(b.x); r[5] = (short)f2bf(b.y);
    r[6] = (short)f2bf(b.z); r[7] = (short)f2bf(b.w);
    return r;
}

// ===========================================================================
// Fused prep: blocks [0, nP1) do CSR bucket partition;
// blocks [nP1, nP1+nCv) do fp32->bf16 feature conversion.
// ===========================================================================
__global__ __launch_bounds__(256) void prep_kernel(
    const int* __restrict__ rows, const int* __restrict__ cols,
    const float* __restrict__ vals,
    int* __restrict__ bktCnt,
    uint2* __restrict__ stagedA, uint2* __restrict__ stagedT,
    const float4* __restrict__ lf, const float4* __restrict__ rf,
    uint2* __restrict__ l16, uint2* __restrict__ r16,
    int nP1, int n4)
{
    const int tid = threadIdx.x;
    if ((int)blockIdx.x >= nP1) {
        int i = (blockIdx.x - nP1) * 256 + tid;
        if (i < n4) {
            float4 a = lf[i];
            float4 b = rf[i];
            l16[i] = make_uint2(pack2bf(a.x, a.y), pack2bf(a.z, a.w));
            r16[i] = make_uint2(pack2bf(b.x, b.y), pack2bf(b.z, b.w));
        }
        return;
    }
    __shared__ int cA[NBKT], cT[NBKT], bA[NBKT], bT[NBKT];
    for (int i = tid; i < NBKT; i += 256) { cA[i] = 0; cT[i] = 0; }
    __syncthreads();

    int r[8], c[8];
    unsigned int v[8];
    const int base = blockIdx.x * 2048 + tid;
    #pragma unroll
    for (int k = 0; k < 8; ++k) {
        int e = base + k * 256;
        bool ok = e < E_EDGES;
        r[k] = ok ? __builtin_nontemporal_load(rows + e) : -1;
        c[k] = ok ? __builtin_nontemporal_load(cols + e) : 0;
        v[k] = ok ? __float_as_uint(__builtin_nontemporal_load(vals + e)) : 0u;
        if (ok) {
            atomicAdd(&cA[r[k] >> 8], 1);
            atomicAdd(&cT[c[k] >> 8], 1);
        }
    }
    __syncthreads();
    for (int i = tid; i < NBKT; i += 256) {
        bA[i] = atomicAdd(&bktCnt[i], cA[i]);
        bT[i] = atomicAdd(&bktCnt[NBKT + i], cT[i]);
        cA[i] = 0; cT[i] = 0;
    }
    __syncthreads();
    #pragma unroll
    for (int k = 0; k < 8; ++k) {
        if (r[k] < 0) continue;
        int ba = r[k] >> 8;
        int pa = bA[ba] + atomicAdd(&cA[ba], 1);
        if (pa < BKT_CAP) {
            unsigned long long rec =
                ((unsigned long long)v[k] << 32) |
                (((unsigned)r[k] << 16) | (unsigned)c[k]);
            __builtin_nontemporal_store(rec,
                (unsigned long long*)(stagedA + (size_t)ba * BKT_CAP + pa));
        }
        int bt = c[k] >> 8;
        int pt = bT[bt] + atomicAdd(&cT[bt], 1);
        if (pt < BKT_CAP) {
            unsigned long long rec =
                ((unsigned long long)v[k] << 32) |
                (((unsigned)c[k] << 16) | (unsigned)r[k]);
            __builtin_nontemporal_store(rec,
                (unsigned long long*)(stagedT + (size_t)bt * BKT_CAP + pt));
        }
    }
}

__global__ __launch_bounds__(256) void bkt_scan(
    const int* __restrict__ bktCnt, int* __restrict__ bktBase,
    int* __restrict__ rpA, int* __restrict__ rpT)
{
    __shared__ int s[2][256];
    const int tid = threadIdx.x;
    for (int d = 0; d < 2; ++d) {
        int v = (tid < NBKT) ? min(bktCnt[d * NBKT + tid], BKT_CAP) : 0;
        s[0][tid] = v;
        __syncthreads();
        int sel = 0;
        for (int off = 1; off < 256; off <<= 1) {
            int t = s[sel][tid] + ((tid >= off) ? s[sel][tid - off] : 0);
            s[sel ^ 1][tid] = t;
            sel ^= 1;
            __syncthreads();
        }
        int incl = s[sel][tid];
        if (tid < NBKT) bktBase[d * NBKT + tid] = incl - v;
        if (tid == NBKT - 1) (d ? rpT : rpA)[N_NODES] = incl;
        __syncthreads();
    }
}

__global__ __launch_bounds__(256) void build_p2(
    const int* __restrict__ bktCnt, const int* __restrict__ bktBase,
    const uint2* __restrict__ stagedA, const uint2* __restrict__ stagedT,
    int* __restrict__ rpA, int* __restrict__ rpT,
    int2* __restrict__ cvA, int2* __restrict__ cvT)
{
    const int tid = threadIdx.x;
    int dir = (int)blockIdx.x >= NBKT;
    int b = blockIdx.x - dir * NBKT;
    int cnt = min(bktCnt[dir * NBKT + b], BKT_CAP);
    int cbase = bktBase[dir * NBKT + b];
    const uint2* staged = (dir ? stagedT : stagedA) + (size_t)b * BKT_CAP;
    int* rp = dir ? rpT : rpA;
    int2* cv = dir ? cvT : cvA;

    __shared__ int rc[256];
    __shared__ int s[2][256];
    rc[tid] = 0;
    __syncthreads();
    for (int i = tid; i < cnt; i += 256)
        atomicAdd(&rc[(staged[i].x >> 16) & 255], 1);
    __syncthreads();
    int own = rc[tid];
    s[0][tid] = own;
    __syncthreads();
    int sel = 0;
    for (int off = 1; off < 256; off <<= 1) {
        int t = s[sel][tid] + ((tid >= off) ? s[sel][tid - off] : 0);
        s[sel ^ 1][tid] = t;
        sel ^= 1;
        __syncthreads();
    }
    int ex = s[sel][tid] - own;
    int row = b * 256 + tid;
    if (row < N_NODES) rp[row] = cbase + ex;
    rc[tid] = ex;
    __syncthreads();
    for (int i = tid; i < cnt; i += 256) {
        uint2 rec = staged[i];
        int local = (rec.x >> 16) & 255;
        int pos = cbase + atomicAdd(&rc[local], 1);
        // store col as BYTE offset (col * 256) for cheap gather addressing
        cv[pos] = make_int2((int)((rec.x & 0xFFFFu) << 8), (int)rec.y);
    }
}

// ===========================================================================
// Generic SpMM: 16 lanes/edge, 16B/lane, 4 edge sub-streams, 4-deep gather
// batch with asm-pinned liveness (rule #17): the empty asm with "+v" on all
// four gather results forces all 4 buffer_loads to issue before any consume
// -> 16 gathers genuinely in flight per wave.
//   t = M @ g16 ; m = t * s16
// Optional prior accumulation: a = pa + t, q = pm + m (in-place safe).
// Stores (nullable): a16 = bf(a), m16 = bf(q), k16 = bf(t + m).
// cv.x holds col*256 (byte offset). Two sets per dispatch (blocks>=nA -> B).
// ===========================================================================
struct SpSet {
    const int* rp;
    const int2* cv;
    const unsigned int* g16;
    const unsigned int* s16;
    const unsigned int* pa16;   // prior a (or null)
    const unsigned int* pm16;   // prior m (or null)
    unsigned int* a16;
    unsigned int* m16;
    unsigned int* k16;
};

__device__ __forceinline__ void sp_accum(float* acc, u32x4 w, float v) {
    float2 f;
    f = unpack2bf(w[0]); acc[0] = fmaf(v, f.x, acc[0]); acc[1] = fmaf(v, f.y, acc[1]);
    f = unpack2bf(w[1]); acc[2] = fmaf(v, f.x, acc[2]); acc[3] = fmaf(v, f.y, acc[3]);
    f = unpack2bf(w[2]); acc[4] = fmaf(v, f.x, acc[4]); acc[5] = fmaf(v, f.y, acc[5]);
    f = unpack2bf(w[3]); acc[6] = fmaf(v, f.x, acc[6]); acc[7] = fmaf(v, f.y, acc[7]);
}

__global__ __launch_bounds__(256) void sp_multi(SpSet sA, SpSet sB, int nA)
{
    bool second = (int)blockIdx.x >= nA;
    SpSet st = second ? sB : sA;
    int blk = second ? (blockIdx.x - nA) : blockIdx.x;
    int row = blk * 4 + (threadIdx.x >> 6);
    if (row >= N_NODES) return;
    int lane = threadIdx.x & 63;
    int li = lane & 15;
    int sub = lane >> 4;

    int b = st.rp[row], e = st.rp[row + 1];
    int o = row * 16 + li;       // uint4 index into row-local streams
    // row-local companion read issued early; overlaps the gather loop
    uint4 sv4 = ((const uint4*)st.s16)[o];

    float acc[8] = {0.f, 0.f, 0.f, 0.f, 0.f, 0.f, 0.f, 0.f};
    const char* gbase = (const char*)st.g16 + li * 16;
    const unsigned long long* cvq = (const unsigned long long*)st.cv;

    int i = b + sub;
    for (; i + 12 < e; i += 16) {
        unsigned long long e0 = cvq[i];
        unsigned long long e1 = cvq[i + 4];
        unsigned long long e2 = cvq[i + 8];
        unsigned long long e3 = cvq[i + 12];
        asm volatile("" : "+v"(e0), "+v"(e1), "+v"(e2), "+v"(e3));
        u32x4 w0 = *(const u32x4*)(gbase + (unsigned)e0);
        u32x4 w1 = *(const u32x4*)(gbase + (unsigned)e1);
        u32x4 w2 = *(const u32x4*)(gbase + (unsigned)e2);
        u32x4 w3 = *(const u32x4*)(gbase + (unsigned)e3);
        asm volatile("" : "+v"(w0), "+v"(w1), "+v"(w2), "+v"(w3));
        sp_accum(acc, w0, __uint_as_float((unsigned)(e0 >> 32)));
        sp_accum(acc, w1, __uint_as_float((unsigned)(e1 >> 32)));
        sp_accum(acc, w2, __uint_as_float((unsigned)(e2 >> 32)));
        sp_accum(acc, w3, __uint_as_float((unsigned)(e3 >> 32)));
    }
    for (; i + 4 < e; i += 8) {
        unsigned long long e0 = cvq[i];
        unsigned long long e1 = cvq[i + 4];
        u32x4 w0 = *(const u32x4*)(gbase + (unsigned)e0);
        u32x4 w1 = *(const u32x4*)(gbase + (unsigned)e1);
        asm volatile("" : "+v"(w0), "+v"(w1));
        sp_accum(acc, w0, __uint_as_float((unsigned)(e0 >> 32)));
        sp_accum(acc, w1, __uint_as_float((unsigned)(e1 >> 32)));
    }
    if (i < e) {
        unsigned long long e0 = cvq[i];
        u32x4 w = *(const u32x4*)(gbase + (unsigned)e0);
        sp_accum(acc, w, __uint_as_float((unsigned)(e0 >> 32)));
    }

    #pragma unroll
    for (int j = 0; j < 8; ++j) {
        acc[j] += __shfl_xor(acc[j], 16, 64);
        acc[j] += __shfl_xor(acc[j], 32, 64);
    }

    float2 s0 = unpack2bf(sv4.x), s1 = unpack2bf(sv4.y);
    float2 s2 = unpack2bf(sv4.z), s3 = unpack2bf(sv4.w);
    float m[8] = {acc[0]*s0.x, acc[1]*s0.y, acc[2]*s1.x, acc[3]*s1.y,
                  acc[4]*s2.x, acc[5]*s2.y, acc[6]*s3.x, acc[7]*s3.y};

    if (sub == 0 && st.a16) {
        float a[8] = {acc[0], acc[1], acc[2], acc[3], acc[4], acc[5], acc[6], acc[7]};
        if (st.pa16) {
            uint4 pv = ((const uint4*)st.pa16)[o];
            float2 p0 = unpack2bf(pv.x), p1 = unpack2bf(pv.y);
            float2 p2 = unpack2bf(pv.z), p3 = unpack2bf(pv.w);
            a[0] += p0.x; a[1] += p0.y; a[2] += p1.x; a[3] += p1.y;
            a[4] += p2.x; a[5] += p2.y; a[6] += p3.x; a[7] += p3.y;
        }
        ((uint4*)st.a16)[o] = make_uint4(
            pack2bf(a[0], a[1]), pack2bf(a[2], a[3]),
            pack2bf(a[4], a[5]), pack2bf(a[6], a[7]));
    } else if (sub == 1 && st.m16) {
        float q[8] = {m[0], m[1], m[2], m[3], m[4], m[5], m[6], m[7]};
        if (st.pm16) {
            uint4 pv = ((const uint4*)st.pm16)[o];
            float2 p0 = unpack2bf(pv.x), p1 = unpack2bf(pv.y);
            float2 p2 = unpack2bf(pv.z), p3 = unpack2bf(pv.w);
            q[0] += p0.x; q[1] += p0.y; q[2] += p1.x; q[3] += p1.y;
            q[4] += p2.x; q[5] += p2.y; q[6] += p3.x; q[7] += p3.y;
        }
        ((uint4*)st.m16)[o] = make_uint4(
            pack2bf(q[0], q[1]), pack2bf(q[2], q[3]),
            pack2bf(q[4], q[5]), pack2bf(q[6], q[7]));
    } else if (sub == 2 && st.k16) {
        ((uint4*)st.k16)[o] = make_uint4(
            pack2bf(acc[0]+m[0], acc[1]+m[1]),
            pack2bf(acc[2]+m[2], acc[3]+m[3]),
            pack2bf(acc[4]+m[4], acc[5]+m[5]),
            pack2bf(acc[6]+m[6], acc[7]+m[7]));
    }
}

// ===========================================================================
// MFMA double GEMM, fragment-linear conflict-free LDS, 128-row blocks:
//   res = relu( X1@W1^T + X2@W2^T + 2*(b1+b2) )
// Two sets per dispatch (blocks >= nA -> set B). 32 KB LDS.
// ===========================================================================
struct G2 {
    const unsigned short* X1[2];
    const unsigned short* X2[2];
    float* outf[2];
    unsigned short* o16[2];
};

__global__ __launch_bounds__(256) void gemm2f(
    G2 g, const float* __restrict__ W1, const float* __restrict__ W2,
    const float* __restrict__ b1, const float* __restrict__ b2, int nA)
{
    __shared__ unsigned short xs[2][64 * DIM];   // 32 KB

    int second = (int)blockIdx.x >= nA;
    int blk = blockIdx.x - second * nA;
    const int tid = threadIdx.x;

    const unsigned short* Xs0 = g.X1[second];
    const unsigned short* Xs1 = g.X2[second];
    float* outf = g.outf[second];
    unsigned short* o16 = g.o16[second];

    const int wv = tid >> 6;
    const int lane = tid & 63;
    const int lr = lane & 15;
    const int kgrp = lane >> 4;
    const int colbase = wv * 32;

    short8 wf[2][2][4];
    #pragma unroll
    for (int mat = 0; mat < 2; ++mat) {
        const float* W = mat ? W2 : W1;
        #pragma unroll
        for (int nt = 0; nt < 2; ++nt) {
            #pragma unroll
            for (int ks = 0; ks < 4; ++ks) {
                const float* wp = W + (size_t)(colbase + nt * 16 + lr) * DIM
                                    + ks * 32 + kgrp * 8;
                wf[mat][nt][ks] = pack_bf8(*(const float4*)wp,
                                           *(const float4*)(wp + 4));
            }
        }
    }

    float cb[2];
    #pragma unroll
    for (int nt = 0; nt < 2; ++nt) {
        int col = colbase + nt * 16 + lr;
        cb[nt] = 2.0f * (b1[col] + b2[col]);
    }

    #pragma unroll
    for (int h = 0; h < 2; ++h) {
        const int row0 = blk * 128 + h * 64;
        if (h) __syncthreads();

        #pragma unroll
        for (int t = 0; t < 2; ++t) {
            const unsigned short* X = t ? Xs1 : Xs0;
            #pragma unroll
            for (int it = 0; it < 4; ++it) {
                int id = tid + 256 * it;
                int r = id >> 4, c16 = id & 15;
                int ks = c16 >> 2, kg = c16 & 3;
                int mt = r >> 4, rr = r & 15;
                int addr = ((((ks * 4 + mt) * 64) + kg * 16 + rr) * 16) ^ (ks << 5);
                int grow = min(row0 + r, N_NODES - 1);
                uint4 d = *(const uint4*)(X + (size_t)grow * DIM + c16 * 8);
                *(uint4*)((char*)&xs[t][0] + addr) = d;
            }
        }
        __syncthreads();

        f32x4 acc[4][2];
        #pragma unroll
        for (int mt = 0; mt < 4; ++mt)
            #pragma unroll
            for (int nt = 0; nt < 2; ++nt)
                acc[mt][nt] = (f32x4){0.f, 0.f, 0.f, 0.f};

        #pragma unroll
        for (int ks = 0; ks < 4; ++ks) {
            short8 a1f[4], a2f[4];
            #pragma unroll
            for (int mt = 0; mt < 4; ++mt) {
                int addr = ((((ks * 4 + mt) * 64) + lane) * 16) ^ (ks << 5);
                a1f[mt] = *(const short8*)((const char*)&xs[0][0] + addr);
                a2f[mt] = *(const short8*)((const char*)&xs[1][0] + addr);
            }
            #pragma unroll
            for (int mt = 0; mt < 4; ++mt) {
                #pragma unroll
                for (int nt = 0; nt < 2; ++nt) {
                    acc[mt][nt] = __builtin_amdgcn_mfma_f32_16x16x32_bf16(
                        a1f[mt], wf[0][nt][ks], acc[mt][nt], 0, 0, 0);
                    acc[mt][nt] = __builtin_amdgcn_mfma_f32_16x16x32_bf16(
                        a2f[mt], wf[1][nt][ks], acc[mt][nt], 0, 0, 0);
                }
            }
        }

        #pragma unroll
        for (int nt = 0; nt < 2; ++nt) {
            int col = colbase + nt * 16 + lr;
            #pragma unroll
            for (int mt = 0; mt < 4; ++mt) {
                #pragma unroll
                for (int r = 0; r < 4; ++r) {
                    int row = row0 + mt * 16 + kgrp * 4 + r;
                    if (row < N_NODES) {
                        float o = fmaxf(acc[mt][nt][r] + cb[nt], 0.f);
                        if (outf) outf[(size_t)row * DIM + col] = o;
                        if (o16) o16[(size_t)row * DIM + col] = f2bf(o);
                    }
                }
            }
        }
    }
}

// ===========================================================================
extern "C" void kernel_launch(void* const* d_in, const int* in_sizes, int n_in,
                              void* d_out, int out_size, void* d_ws, size_t ws_size,
                              hipStream_t stream)
{
    const float* l_feat = (const float*)d_in[0];
    const float* r_feat = (const float*)d_in[1];
    const int*   rows   = (const int*)d_in[2];
    const int*   cols   = (const int*)d_in[3];
    const float* vals   = (const float*)d_in[4];
    const float* W1a    = (const float*)d_in[5];
    const float* b1a    = (const float*)d_in[6];
    const float* W2a    = (const float*)d_in[7];
    const float* b2a    = (const float*)d_in[8];
    const float* W1b    = (const float*)d_in[9];
    const float* b1b    = (const float*)d_in[10];
    const float* W2b    = (const float*)d_in[11];
    const float* b2b    = (const float*)d_in[12];
    float* out = (float*)d_out;

    const size_t NT = (size_t)N_NODES * DIM;
    const size_t MAT16 = NT * 2;

    char* p = (char*)d_ws;
    auto alloc = [&](size_t bytes) {
        char* q = p; p += (bytes + 255) & ~(size_t)255; return q;
    };
    unsigned int* l16 = (unsigned int*)alloc(MAT16);   // l_feat -> y1
    unsigned int* r16 = (unsigned int*)alloc(MAT16);   // r_feat -> z1
    unsigned int* Kl  = (unsigned int*)alloc(MAT16);
    unsigned int* Kr  = (unsigned int*)alloc(MAT16);
    unsigned int* aL  = (unsigned int*)alloc(MAT16);   // a-sum (L)
    unsigned int* mL  = (unsigned int*)alloc(MAT16);   // m-sum (L)
    unsigned int* aR  = (unsigned int*)alloc(MAT16);   // a-sum (R)
    unsigned int* mR  = (unsigned int*)alloc(MAT16);   // m-sum (R)
    int* rpA = (int*)alloc((size_t)(N_NODES + 1) * 4);
    int* rpT = (int*)alloc((size_t)(N_NODES + 1) * 4);
    int* bktCnt  = (int*)alloc((size_t)(2 * NBKT) * 4);
    int* bktBase = (int*)alloc((size_t)(2 * NBKT) * 4);
    int2* cvA = (int2*)alloc((size_t)E_EDGES * 8);
    int2* cvT = (int2*)alloc((size_t)E_EDGES * 8);
    uint2* stagedA = (uint2*)alloc((size_t)NBKT * BKT_CAP * 8);
    uint2* stagedT = (uint2*)alloc((size_t)NBKT * BKT_CAP * 8);

    const int n4 = (int)(NT / 4);
    dim3 blk(256);
    const int cvBlocks = (n4 + 255) / 256;         // 5000
    const int spBlocks = (N_NODES + 3) / 4;        // 10000
    const int gmBlocks = (N_NODES + 127) / 128;    // 313
    const int p1Blocks = (E_EDGES + 2047) / 2048;  // 313

    // ---- CSR build + bf16 conversion (fused) ----
    hipMemsetAsync(bktCnt, 0, (size_t)(2 * NBKT) * 4, stream);
    prep_kernel<<<dim3(p1Blocks + cvBlocks), blk, 0, stream>>>(
        rows, cols, vals, bktCnt, stagedA, stagedT,
        (const float4*)l_feat, (const float4*)r_feat,
        (uint2*)l16, (uint2*)r16, p1Blocks, n4);
    bkt_scan<<<1, blk, 0, stream>>>(bktCnt, bktBase, rpA, rpT);
    build_p2<<<dim3(2 * NBKT), blk, 0, stream>>>(
        bktCnt, bktBase, stagedA, stagedT, rpA, rpT, cvA, cvT);

    // ======================= Layer A =======================
    {   // hop0: a0=A@r (store a,m,Kl) ; b0=AT@l (store a,m,Kr)
        SpSet h0A = {rpA, cvA, r16, l16, nullptr, nullptr, aL, mL, Kl};
        SpSet h0T = {rpT, cvT, l16, r16, nullptr, nullptr, aR, mR, Kr};
        sp_multi<<<dim3(2 * spBlocks), blk, 0, stream>>>(h0A, h0T, spBlocks);
    }
    {   // hop1 (accumulate in place): aL=bf(aL+t), mL=bf(mL+t*Kl); same for R
        SpSet h1A = {rpA, cvA, Kr, Kl, aL, mL, aL, mL, nullptr};
        SpSet h1T = {rpT, cvT, Kl, Kr, aR, mR, aR, mR, nullptr};
        sp_multi<<<dim3(2 * spBlocks), blk, 0, stream>>>(h1A, h1T, spBlocks);
    }
    {   // y1 -> l16 (bf16), z1 -> r16 (bf16)
        G2 g;
        g.X1[0] = (const unsigned short*)aL; g.X2[0] = (const unsigned short*)mL;
        g.X1[1] = (const unsigned short*)aR; g.X2[1] = (const unsigned short*)mR;
        g.outf[0] = nullptr; g.outf[1] = nullptr;
        g.o16[0] = (unsigned short*)l16;
        g.o16[1] = (unsigned short*)r16;
        gemm2f<<<dim3(2 * gmBlocks), blk, 0, stream>>>(
            g, W1a, W2a, b1a, b2a, gmBlocks);
    }

    // ======================= Layer B (l-output only) =======================
    {   // a=A@z1 (store a,m,Klb) ; b=AT@y1 (store Krb only)
        SpSet b0A = {rpA, cvA, r16, l16, nullptr, nullptr, aL, mL, Kl};
        SpSet b0T = {rpT, cvT, l16, r16, nullptr, nullptr, nullptr, nullptr, Kr};
        sp_multi<<<dim3(2 * spBlocks), blk, 0, stream>>>(b0A, b0T, spBlocks);
    }
    {   // hop1: aL=bf(aL+t), mL=bf(mL+t*Klb)
        SpSet b1A = {rpA, cvA, Kr, Kl, aL, mL, aL, mL, nullptr};
        sp_multi<<<dim3(spBlocks), blk, 0, stream>>>(b1A, b1A, spBlocks);
    }
    {   // out = relu(aL@W1b^T + mL@W2b^T + 2(b1b+b2b))  [fp32]
        G2 g;
        g.X1[0] = (const unsigned short*)aL; g.X2[0] = (const unsigned short*)mL;
        g.X1[1] = g.X1[0]; g.X2[1] = g.X2[0];
        g.outf[0] = out; g.outf[1] = nullptr;
        g.o16[0] = nullptr; g.o16[1] = nullptr;
        gemm2f<<<dim3(gmBlocks), blk, 0, stream>>>(
            g, W1b, W2b, b1b, b2b, gmBlocks);
    }
}

// Round 12
// 309.911 us; speedup vs baseline: 1.0987x; 1.0077x over previous
//
#include <hip/hip_runtime.h>

#define N_NODES 40000
#define E_EDGES 640000
#define DIM 128
#define NBKT 157            // buckets of 256 rows
#define BKT_CAP 6144

typedef __attribute__((ext_vector_type(8))) short short8;
typedef __attribute__((ext_vector_type(4))) float f32x4;
typedef __attribute__((ext_vector_type(4))) unsigned int u32x4;

__device__ __forceinline__ unsigned short f2bf(float f) {
    unsigned int u = __float_as_uint(f);
    u = u + 0x7FFFu + ((u >> 16) & 1u);
    return (unsigned short)(u >> 16);
}
__device__ __forceinline__ unsigned int pack2bf(float lo, float hi) {
    return (unsigned int)f2bf(lo) | ((unsigned int)f2bf(hi) << 16);
}
__device__ __forceinline__ float2 unpack2bf(unsigned int u) {
    return make_float2(__uint_as_float(u << 16), __uint_as_float(u & 0xFFFF0000u));
}
__device__ __forceinline__ short8 pack_bf8(float4 a, float4 b) {
    short8 r;
    r[0] = (short)f2bf(a.x); r[1] = (short)f2bf(a.y);
    r[2] = (short)f2bf(a.z); r[3] = (short)f2bf(a.w);
    r[4] = (short)f2bf(b.x); r[5] = (short)f2bf(b.y);
    r[6] = (short)f2bf(b.z); r[7] = (short)f2bf(b.w);
    return r;
}

// ===========================================================================
// Fused prep: blocks [0, nP1) do CSR bucket partition;
// blocks [nP1, nP1+nCv) do fp32->bf16 feature conversion.
// ===========================================================================
__global__ __launch_bounds__(256) void prep_kernel(
    const int* __restrict__ rows, const int* __restrict__ cols,
    const float* __restrict__ vals,
    int* __restrict__ bktCnt,
    uint2* __restrict__ stagedA, uint2* __restrict__ stagedT,
    const float4* __restrict__ lf, const float4* __restrict__ rf,
    uint2* __restrict__ l16, uint2* __restrict__ r16,
    int nP1, int n4)
{
    const int tid = threadIdx.x;
    if ((int)blockIdx.x >= nP1) {
        int i = (blockIdx.x - nP1) * 256 + tid;
        if (i < n4) {
            float4 a = lf[i];
            float4 b = rf[i];
            l16[i] = make_uint2(pack2bf(a.x, a.y), pack2bf(a.z, a.w));
            r16[i] = make_uint2(pack2bf(b.x, b.y), pack2bf(b.z, b.w));
        }
        return;
    }
    __shared__ int cA[NBKT], cT[NBKT], bA[NBKT], bT[NBKT];
    for (int i = tid; i < NBKT; i += 256) { cA[i] = 0; cT[i] = 0; }
    __syncthreads();

    int r[8], c[8];
    unsigned int v[8];
    const int base = blockIdx.x * 2048 + tid;
    #pragma unroll
    for (int k = 0; k < 8; ++k) {
        int e = base + k * 256;
        bool ok = e < E_EDGES;
        r[k] = ok ? __builtin_nontemporal_load(rows + e) : -1;
        c[k] = ok ? __builtin_nontemporal_load(cols + e) : 0;
        v[k] = ok ? __float_as_uint(__builtin_nontemporal_load(vals + e)) : 0u;
        if (ok) {
            atomicAdd(&cA[r[k] >> 8], 1);
            atomicAdd(&cT[c[k] >> 8], 1);
        }
    }
    __syncthreads();
    for (int i = tid; i < NBKT; i += 256) {
        bA[i] = atomicAdd(&bktCnt[i], cA[i]);
        bT[i] = atomicAdd(&bktCnt[NBKT + i], cT[i]);
        cA[i] = 0; cT[i] = 0;
    }
    __syncthreads();
    #pragma unroll
    for (int k = 0; k < 8; ++k) {
        if (r[k] < 0) continue;
        int ba = r[k] >> 8;
        int pa = bA[ba] + atomicAdd(&cA[ba], 1);
        if (pa < BKT_CAP) {
            unsigned long long rec =
                ((unsigned long long)v[k] << 32) |
                (((unsigned)r[k] << 16) | (unsigned)c[k]);
            __builtin_nontemporal_store(rec,
                (unsigned long long*)(stagedA + (size_t)ba * BKT_CAP + pa));
        }
        int bt = c[k] >> 8;
        int pt = bT[bt] + atomicAdd(&cT[bt], 1);
        if (pt < BKT_CAP) {
            unsigned long long rec =
                ((unsigned long long)v[k] << 32) |
                (((unsigned)c[k] << 16) | (unsigned)r[k]);
            __builtin_nontemporal_store(rec,
                (unsigned long long*)(stagedT + (size_t)bt * BKT_CAP + pt));
        }
    }
}

__global__ __launch_bounds__(256) void bkt_scan(
    const int* __restrict__ bktCnt, int* __restrict__ bktBase,
    int* __restrict__ rpA, int* __restrict__ rpT)
{
    __shared__ int s[2][256];
    const int tid = threadIdx.x;
    for (int d = 0; d < 2; ++d) {
        int v = (tid < NBKT) ? min(bktCnt[d * NBKT + tid], BKT_CAP) : 0;
        s[0][tid] = v;
        __syncthreads();
        int sel = 0;
        for (int off = 1; off < 256; off <<= 1) {
            int t = s[sel][tid] + ((tid >= off) ? s[sel][tid - off] : 0);
            s[sel ^ 1][tid] = t;
            sel ^= 1;
            __syncthreads();
        }
        int incl = s[sel][tid];
        if (tid < NBKT) bktBase[d * NBKT + tid] = incl - v;
        if (tid == NBKT - 1) (d ? rpT : rpA)[N_NODES] = incl;
        __syncthreads();
    }
}

__global__ __launch_bounds__(256) void build_p2(
    const int* __restrict__ bktCnt, const int* __restrict__ bktBase,
    const uint2* __restrict__ stagedA, const uint2* __restrict__ stagedT,
    int* __restrict__ rpA, int* __restrict__ rpT,
    int2* __restrict__ cvA, int2* __restrict__ cvT)
{
    const int tid = threadIdx.x;
    int dir = (int)blockIdx.x >= NBKT;
    int b = blockIdx.x - dir * NBKT;
    int cnt = min(bktCnt[dir * NBKT + b], BKT_CAP);
    int cbase = bktBase[dir * NBKT + b];
    const uint2* staged = (dir ? stagedT : stagedA) + (size_t)b * BKT_CAP;
    int* rp = dir ? rpT : rpA;
    int2* cv = dir ? cvT : cvA;

    __shared__ int rc[256];
    __shared__ int s[2][256];
    rc[tid] = 0;
    __syncthreads();
    for (int i = tid; i < cnt; i += 256)
        atomicAdd(&rc[(staged[i].x >> 16) & 255], 1);
    __syncthreads();
    int own = rc[tid];
    s[0][tid] = own;
    __syncthreads();
    int sel = 0;
    for (int off = 1; off < 256; off <<= 1) {
        int t = s[sel][tid] + ((tid >= off) ? s[sel][tid - off] : 0);
        s[sel ^ 1][tid] = t;
        sel ^= 1;
        __syncthreads();
    }
    int ex = s[sel][tid] - own;
    int row = b * 256 + tid;
    if (row < N_NODES) rp[row] = cbase + ex;
    rc[tid] = ex;
    __syncthreads();
    for (int i = tid; i < cnt; i += 256) {
        uint2 rec = staged[i];
        int local = (rec.x >> 16) & 255;
        int pos = cbase + atomicAdd(&rc[local], 1);
        // store col as BYTE offset (col * 256) for cheap gather addressing
        cv[pos] = make_int2((int)((rec.x & 0xFFFFu) << 8), (int)rec.y);
    }
}

// ===========================================================================
// Generic SpMM: 16 lanes/edge, 16B/lane, 4 edge sub-streams.
//   t = M @ g16 ; m = t * s16
// Optional prior accumulation: a = pa + t, q = pm + m (in-place safe).
// Stores (nullable): a16 = bf(a), m16 = bf(q), k16 = bf(t + m).
// cv.x holds col*256 (byte offset).
// Set selection: xcdsplit=1 -> XCD-partitioned (set A on XCDs 0-3, set B on
// XCDs 4-7, exploiting round-robin block->XCD dispatch) so each XCD's 4MB L2
// caches ONE 10.25MB gather matrix instead of both. xcdsplit=0 -> linear.
// ===========================================================================
struct SpSet {
    const int* rp;
    const int2* cv;
    const unsigned int* g16;
    const unsigned int* s16;
    const unsigned int* pa16;   // prior a (or null)
    const unsigned int* pm16;   // prior m (or null)
    unsigned int* a16;
    unsigned int* m16;
    unsigned int* k16;
};

__device__ __forceinline__ void sp_accum(float* acc, u32x4 w, float v) {
    float2 f;
    f = unpack2bf(w[0]); acc[0] = fmaf(v, f.x, acc[0]); acc[1] = fmaf(v, f.y, acc[1]);
    f = unpack2bf(w[1]); acc[2] = fmaf(v, f.x, acc[2]); acc[3] = fmaf(v, f.y, acc[3]);
    f = unpack2bf(w[2]); acc[4] = fmaf(v, f.x, acc[4]); acc[5] = fmaf(v, f.y, acc[5]);
    f = unpack2bf(w[3]); acc[6] = fmaf(v, f.x, acc[6]); acc[7] = fmaf(v, f.y, acc[7]);
}

__global__ __launch_bounds__(256) void sp_multi(SpSet sA, SpSet sB, int nA, int xcdsplit)
{
    bool second;
    int blk;
    if (xcdsplit) {
        int g = blockIdx.x >> 3, r = blockIdx.x & 7;
        second = (r >= 4);
        blk = g * 4 + (r & 3);
    } else {
        second = (int)blockIdx.x >= nA;
        blk = second ? (blockIdx.x - nA) : blockIdx.x;
    }
    SpSet st = second ? sB : sA;
    int row = blk * 4 + (threadIdx.x >> 6);
    if (row >= N_NODES) return;
    int lane = threadIdx.x & 63;
    int li = lane & 15;
    int sub = lane >> 4;

    int b = st.rp[row], e = st.rp[row + 1];
    int o = row * 16 + li;       // uint4 index into row-local streams
    // row-local companion read issued early; overlaps the gather loop
    uint4 sv4 = ((const uint4*)st.s16)[o];

    float acc[8] = {0.f, 0.f, 0.f, 0.f, 0.f, 0.f, 0.f, 0.f};
    const char* gbase = (const char*)st.g16 + li * 16;
    const unsigned long long* cvq = (const unsigned long long*)st.cv;

    int i = b + sub;
    for (; i + 12 < e; i += 16) {
        unsigned long long e0 = cvq[i];
        unsigned long long e1 = cvq[i + 4];
        unsigned long long e2 = cvq[i + 8];
        unsigned long long e3 = cvq[i + 12];
        asm volatile("" : "+v"(e0), "+v"(e1), "+v"(e2), "+v"(e3));
        u32x4 w0 = *(const u32x4*)(gbase + (unsigned)e0);
        u32x4 w1 = *(const u32x4*)(gbase + (unsigned)e1);
        u32x4 w2 = *(const u32x4*)(gbase + (unsigned)e2);
        u32x4 w3 = *(const u32x4*)(gbase + (unsigned)e3);
        asm volatile("" : "+v"(w0), "+v"(w1), "+v"(w2), "+v"(w3));
        sp_accum(acc, w0, __uint_as_float((unsigned)(e0 >> 32)));
        sp_accum(acc, w1, __uint_as_float((unsigned)(e1 >> 32)));
        sp_accum(acc, w2, __uint_as_float((unsigned)(e2 >> 32)));
        sp_accum(acc, w3, __uint_as_float((unsigned)(e3 >> 32)));
    }
    for (; i + 4 < e; i += 8) {
        unsigned long long e0 = cvq[i];
        unsigned long long e1 = cvq[i + 4];
        u32x4 w0 = *(const u32x4*)(gbase + (unsigned)e0);
        u32x4 w1 = *(const u32x4*)(gbase + (unsigned)e1);
        asm volatile("" : "+v"(w0), "+v"(w1));
        sp_accum(acc, w0, __uint_as_float((unsigned)(e0 >> 32)));
        sp_accum(acc, w1, __uint_as_float((unsigned)(e1 >> 32)));
    }
    if (i < e) {
        unsigned long long e0 = cvq[i];
        u32x4 w = *(const u32x4*)(gbase + (unsigned)e0);
        sp_accum(acc, w, __uint_as_float((unsigned)(e0 >> 32)));
    }

    #pragma unroll
    for (int j = 0; j < 8; ++j) {
        acc[j] += __shfl_xor(acc[j], 16, 64);
        acc[j] += __shfl_xor(acc[j], 32, 64);
    }

    float2 s0 = unpack2bf(sv4.x), s1 = unpack2bf(sv4.y);
    float2 s2 = unpack2bf(sv4.z), s3 = unpack2bf(sv4.w);
    float m[8] = {acc[0]*s0.x, acc[1]*s0.y, acc[2]*s1.x, acc[3]*s1.y,
                  acc[4]*s2.x, acc[5]*s2.y, acc[6]*s3.x, acc[7]*s3.y};

    if (sub == 0 && st.a16) {
        float a[8] = {acc[0], acc[1], acc[2], acc[3], acc[4], acc[5], acc[6], acc[7]};
        if (st.pa16) {
            uint4 pv = ((const uint4*)st.pa16)[o];
            float2 p0 = unpack2bf(pv.x), p1 = unpack2bf(pv.y);
            float2 p2 = unpack2bf(pv.z), p3 = unpack2bf(pv.w);
            a[0] += p0.x; a[1] += p0.y; a[2] += p1.x; a[3] += p1.y;
            a[4] += p2.x; a[5] += p2.y; a[6] += p3.x; a[7] += p3.y;
        }
        ((uint4*)st.a16)[o] = make_uint4(
            pack2bf(a[0], a[1]), pack2bf(a[2], a[3]),
            pack2bf(a[4], a[5]), pack2bf(a[6], a[7]));
    } else if (sub == 1 && st.m16) {
        float q[8] = {m[0], m[1], m[2], m[3], m[4], m[5], m[6], m[7]};
        if (st.pm16) {
            uint4 pv = ((const uint4*)st.pm16)[o];
            float2 p0 = unpack2bf(pv.x), p1 = unpack2bf(pv.y);
            float2 p2 = unpack2bf(pv.z), p3 = unpack2bf(pv.w);
            q[0] += p0.x; q[1] += p0.y; q[2] += p1.x; q[3] += p1.y;
            q[4] += p2.x; q[5] += p2.y; q[6] += p3.x; q[7] += p3.y;
        }
        ((uint4*)st.m16)[o] = make_uint4(
            pack2bf(q[0], q[1]), pack2bf(q[2], q[3]),
            pack2bf(q[4], q[5]), pack2bf(q[6], q[7]));
    } else if (sub == 2 && st.k16) {
        ((uint4*)st.k16)[o] = make_uint4(
            pack2bf(acc[0]+m[0], acc[1]+m[1]),
            pack2bf(acc[2]+m[2], acc[3]+m[3]),
            pack2bf(acc[4]+m[4], acc[5]+m[5]),
            pack2bf(acc[6]+m[6], acc[7]+m[7]));
    }
}

// ===========================================================================
// MFMA double GEMM, fragment-linear conflict-free LDS, 128-row blocks:
//   res = relu( X1@W1^T + X2@W2^T + 2*(b1+b2) )
// Two sets per dispatch (blocks >= nA -> set B). 32 KB LDS.
// ===========================================================================
struct G2 {
    const unsigned short* X1[2];
    const unsigned short* X2[2];
    float* outf[2];
    unsigned short* o16[2];
};

__global__ __launch_bounds__(256) void gemm2f(
    G2 g, const float* __restrict__ W1, const float* __restrict__ W2,
    const float* __restrict__ b1, const float* __restrict__ b2, int nA)
{
    __shared__ unsigned short xs[2][64 * DIM];   // 32 KB

    int second = (int)blockIdx.x >= nA;
    int blk = blockIdx.x - second * nA;
    const int tid = threadIdx.x;

    const unsigned short* Xs0 = g.X1[second];
    const unsigned short* Xs1 = g.X2[second];
    float* outf = g.outf[second];
    unsigned short* o16 = g.o16[second];

    const int wv = tid >> 6;
    const int lane = tid & 63;
    const int lr = lane & 15;
    const int kgrp = lane >> 4;
    const int colbase = wv * 32;

    short8 wf[2][2][4];
    #pragma unroll
    for (int mat = 0; mat < 2; ++mat) {
        const float* W = mat ? W2 : W1;
        #pragma unroll
        for (int nt = 0; nt < 2; ++nt) {
            #pragma unroll
            for (int ks = 0; ks < 4; ++ks) {
                const float* wp = W + (size_t)(colbase + nt * 16 + lr) * DIM
                                    + ks * 32 + kgrp * 8;
                wf[mat][nt][ks] = pack_bf8(*(const float4*)wp,
                                           *(const float4*)(wp + 4));
            }
        }
    }

    float cb[2];
    #pragma unroll
    for (int nt = 0; nt < 2; ++nt) {
        int col = colbase + nt * 16 + lr;
        cb[nt] = 2.0f * (b1[col] + b2[col]);
    }

    #pragma unroll
    for (int h = 0; h < 2; ++h) {
        const int row0 = blk * 128 + h * 64;
        if (h) __syncthreads();

        #pragma unroll
        for (int t = 0; t < 2; ++t) {
            const unsigned short* X = t ? Xs1 : Xs0;
            #pragma unroll
            for (int it = 0; it < 4; ++it) {
                int id = tid + 256 * it;
                int r = id >> 4, c16 = id & 15;
                int ks = c16 >> 2, kg = c16 & 3;
                int mt = r >> 4, rr = r & 15;
                int addr = ((((ks * 4 + mt) * 64) + kg * 16 + rr) * 16) ^ (ks << 5);
                int grow = min(row0 + r, N_NODES - 1);
                uint4 d = *(const uint4*)(X + (size_t)grow * DIM + c16 * 8);
                *(uint4*)((char*)&xs[t][0] + addr) = d;
            }
        }
        __syncthreads();

        f32x4 acc[4][2];
        #pragma unroll
        for (int mt = 0; mt < 4; ++mt)
            #pragma unroll
            for (int nt = 0; nt < 2; ++nt)
                acc[mt][nt] = (f32x4){0.f, 0.f, 0.f, 0.f};

        #pragma unroll
        for (int ks = 0; ks < 4; ++ks) {
            short8 a1f[4], a2f[4];
            #pragma unroll
            for (int mt = 0; mt < 4; ++mt) {
                int addr = ((((ks * 4 + mt) * 64) + lane) * 16) ^ (ks << 5);
                a1f[mt] = *(const short8*)((const char*)&xs[0][0] + addr);
                a2f[mt] = *(const short8*)((const char*)&xs[1][0] + addr);
            }
            #pragma unroll
            for (int mt = 0; mt < 4; ++mt) {
                #pragma unroll
                for (int nt = 0; nt < 2; ++nt) {
                    acc[mt][nt] = __builtin_amdgcn_mfma_f32_16x16x32_bf16(
                        a1f[mt], wf[0][nt][ks], acc[mt][nt], 0, 0, 0);
                    acc[mt][nt] = __builtin_amdgcn_mfma_f32_16x16x32_bf16(
                        a2f[mt], wf[1][nt][ks], acc[mt][nt], 0, 0, 0);
                }
            }
        }

        #pragma unroll
        for (int nt = 0; nt < 2; ++nt) {
            int col = colbase + nt * 16 + lr;
            #pragma unroll
            for (int mt = 0; mt < 4; ++mt) {
                #pragma unroll
                for (int r = 0; r < 4; ++r) {
                    int row = row0 + mt * 16 + kgrp * 4 + r;
                    if (row < N_NODES) {
                        float o = fmaxf(acc[mt][nt][r] + cb[nt], 0.f);
                        if (outf) outf[(size_t)row * DIM + col] = o;
                        if (o16) o16[(size_t)row * DIM + col] = f2bf(o);
                    }
                }
            }
        }
    }
}

// ===========================================================================
extern "C" void kernel_launch(void* const* d_in, const int* in_sizes, int n_in,
                              void* d_out, int out_size, void* d_ws, size_t ws_size,
                              hipStream_t stream)
{
    const float* l_feat = (const float*)d_in[0];
    const float* r_feat = (const float*)d_in[1];
    const int*   rows   = (const int*)d_in[2];
    const int*   cols   = (const int*)d_in[3];
    const float* vals   = (const float*)d_in[4];
    const float* W1a    = (const float*)d_in[5];
    const float* b1a    = (const float*)d_in[6];
    const float* W2a    = (const float*)d_in[7];
    const float* b2a    = (const float*)d_in[8];
    const float* W1b    = (const float*)d_in[9];
    const float* b1b    = (const float*)d_in[10];
    const float* W2b    = (const float*)d_in[11];
    const float* b2b    = (const float*)d_in[12];
    float* out = (float*)d_out;

    const size_t NT = (size_t)N_NODES * DIM;
    const size_t MAT16 = NT * 2;

    char* p = (char*)d_ws;
    auto alloc = [&](size_t bytes) {
        char* q = p; p += (bytes + 255) & ~(size_t)255; return q;
    };
    unsigned int* l16 = (unsigned int*)alloc(MAT16);   // l_feat -> y1
    unsigned int* r16 = (unsigned int*)alloc(MAT16);   // r_feat -> z1
    unsigned int* Kl  = (unsigned int*)alloc(MAT16);
    unsigned int* Kr  = (unsigned int*)alloc(MAT16);
    unsigned int* aL  = (unsigned int*)alloc(MAT16);   // a-sum (L)
    unsigned int* mL  = (unsigned int*)alloc(MAT16);   // m-sum (L)
    unsigned int* aR  = (unsigned int*)alloc(MAT16);   // a-sum (R)
    unsigned int* mR  = (unsigned int*)alloc(MAT16);   // m-sum (R)
    int* rpA = (int*)alloc((size_t)(N_NODES + 1) * 4);
    int* rpT = (int*)alloc((size_t)(N_NODES + 1) * 4);
    int* bktCnt  = (int*)alloc((size_t)(2 * NBKT) * 4);
    int* bktBase = (int*)alloc((size_t)(2 * NBKT) * 4);
    int2* cvA = (int2*)alloc((size_t)E_EDGES * 8);
    int2* cvT = (int2*)alloc((size_t)E_EDGES * 8);
    uint2* stagedA = (uint2*)alloc((size_t)NBKT * BKT_CAP * 8);
    uint2* stagedT = (uint2*)alloc((size_t)NBKT * BKT_CAP * 8);

    const int n4 = (int)(NT / 4);
    dim3 blk(256);
    const int cvBlocks = (n4 + 255) / 256;         // 5000
    const int spBlocks = (N_NODES + 3) / 4;        // 10000
    const int gmBlocks = (N_NODES + 127) / 128;    // 313
    const int p1Blocks = (E_EDGES + 2047) / 2048;  // 313

    // ---- CSR build + bf16 conversion (fused) ----
    hipMemsetAsync(bktCnt, 0, (size_t)(2 * NBKT) * 4, stream);
    prep_kernel<<<dim3(p1Blocks + cvBlocks), blk, 0, stream>>>(
        rows, cols, vals, bktCnt, stagedA, stagedT,
        (const float4*)l_feat, (const float4*)r_feat,
        (uint2*)l16, (uint2*)r16, p1Blocks, n4);
    bkt_scan<<<1, blk, 0, stream>>>(bktCnt, bktBase, rpA, rpT);
    build_p2<<<dim3(2 * NBKT), blk, 0, stream>>>(
        bktCnt, bktBase, stagedA, stagedT, rpA, rpT, cvA, cvT);

    // ======================= Layer A =======================
    {   // hop0: a0=A@r (store a,m,Kl) ; b0=AT@l (store a,m,Kr)
        SpSet h0A = {rpA, cvA, r16, l16, nullptr, nullptr, aL, mL, Kl};
        SpSet h0T = {rpT, cvT, l16, r16, nullptr, nullptr, aR, mR, Kr};
        sp_multi<<<dim3(2 * spBlocks), blk, 0, stream>>>(h0A, h0T, spBlocks, 1);
    }
    {   // hop1 (accumulate in place): aL=bf(aL+t), mL=bf(mL+t*Kl); same for R
        SpSet h1A = {rpA, cvA, Kr, Kl, aL, mL, aL, mL, nullptr};
        SpSet h1T = {rpT, cvT, Kl, Kr, aR, mR, aR, mR, nullptr};
        sp_multi<<<dim3(2 * spBlocks), blk, 0, stream>>>(h1A, h1T, spBlocks, 1);
    }
    {   // y1 -> l16 (bf16), z1 -> r16 (bf16)
        G2 g;
        g.X1[0] = (const unsigned short*)aL; g.X2[0] = (const unsigned short*)mL;
        g.X1[1] = (const unsigned short*)aR; g.X2[1] = (const unsigned short*)mR;
        g.outf[0] = nullptr; g.outf[1] = nullptr;
        g.o16[0] = (unsigned short*)l16;
        g.o16[1] = (unsigned short*)r16;
        gemm2f<<<dim3(2 * gmBlocks), blk, 0, stream>>>(
            g, W1a, W2a, b1a, b2a, gmBlocks);
    }

    // ======================= Layer B (l-output only) =======================
    {   // a=A@z1 (store a,m,Klb) ; b=AT@y1 (store Krb only)
        SpSet b0A = {rpA, cvA, r16, l16, nullptr, nullptr, aL, mL, Kl};
        SpSet b0T = {rpT, cvT, l16, r16, nullptr, nullptr, nullptr, nullptr, Kr};
        sp_multi<<<dim3(2 * spBlocks), blk, 0, stream>>>(b0A, b0T, spBlocks, 1);
    }
    {   // hop1: aL=bf(aL+t), mL=bf(mL+t*Klb)
        SpSet b1A = {rpA, cvA, Kr, Kl, aL, mL, aL, mL, nullptr};
        sp_multi<<<dim3(spBlocks), blk, 0, stream>>>(b1A, b1A, spBlocks, 0);
    }
    {   // out = relu(aL@W1b^T + mL@W2b^T + 2(b1b+b2b))  [fp32]
        G2 g;
        g.X1[0] = (const unsigned short*)aL; g.X2[0] = (const unsigned short*)mL;
        g.X1[1] = g.X1[0]; g.X2[1] = g.X2[0];
        g.outf[0] = out; g.outf[1] = nullptr;
        g.o16[0] = nullptr; g.o16[1] = nullptr;
        gemm2f<<<dim3(gmBlocks), blk, 0, stream>>>(
            g, W1b, W2b, b1b, b2b, gmBlocks);
    }
}